// Round 11
// baseline (76.969 us; speedup 1.0000x reference)
//
#include <hip/hip_runtime.h>
#include <hip/hip_bf16.h>
#include <stdint.h>

#define B_  4
#define L_  1024
#define C_  512
#define D_  64
#define BH_ 32
#define M_  4096

typedef short  bf16x8 __attribute__((ext_vector_type(8)));
typedef float  f32x4  __attribute__((ext_vector_type(4)));
typedef unsigned short u16x8 __attribute__((ext_vector_type(8)));
typedef unsigned int   u32x2 __attribute__((ext_vector_type(2)));

__device__ __forceinline__ unsigned short f2bf(float f) {
    union { float f; uint32_t u; } v; v.f = f;
    uint32_t u = v.u;
    return (unsigned short)((u + 0x7fffu + ((u >> 16) & 1u)) >> 16);
}
__device__ __forceinline__ float bf2f(unsigned short s) {
    union { uint32_t u; float f; } v; v.u = ((uint32_t)s) << 16;
    return v.f;
}

// async global->LDS, 16B per lane; LDS dest = wave-uniform base (+ implicit lane*16)
__device__ __forceinline__ void gload16(const void* g, void* s) {
    __builtin_amdgcn_global_load_lds((const __attribute__((address_space(1))) void*)g,
                                     (__attribute__((address_space(3))) void*)s, 16, 0, 0);
}

// ---------------- fused f32 -> bf16 convert for x, W_qkv, W_proj ----------------
#define NX4   (M_ * C_ / 4)            // 524288
#define NWQ4  (3 * C_ * C_ / 4)        // 196608
#define NWP4  (C_ * C_ / 4)            // 65536
__global__ void cvt_all(const float* __restrict__ x, const float* __restrict__ wq,
                        const float* __restrict__ wp,
                        unsigned short* __restrict__ xb, unsigned short* __restrict__ wqb,
                        unsigned short* __restrict__ wpb) {
    int i = blockIdx.x * 256 + threadIdx.x;
    const float* src; unsigned short* dst; int o;
    if (i < NX4) { src = x; dst = xb; o = i; }
    else if (i < NX4 + NWQ4) { src = wq; dst = wqb; o = i - NX4; }
    else if (i < NX4 + NWQ4 + NWP4) { src = wp; dst = wpb; o = i - NX4 - NWQ4; }
    else return;
    float4 v = ((const float4*)src)[o];
    ushort4 r;
    r.x = f2bf(v.x); r.y = f2bf(v.y); r.z = f2bf(v.z); r.w = f2bf(v.w);
    ((ushort4*)dst)[o] = r;
}

// ---------------- fused: qkv GEMM (768 tile-blocks) + prep_e (1024 tile-blocks) ----------------
// Independent bodies packed into one launch so the MFMA-bound GEMM and the BW/exp-bound
// prep_e overlap on every CU. Interleave 3:4 via blockIdx%7. Shared LDS union: 24 KB.
// GEMM: qkv[M,1536] = xb[M,512] * wqkvb[1536,512]^T, 64x128 tiles, scatter epilogue.
// prep_e (round-6 version): EI[b][q16][k16][lane][ef x4|eb x4] bf16;
//   lane l=(c,g), elem e: q = q16*16 + c, k = k16*16 + 4g + e.
__global__ __launch_bounds__(256, 2) void fused_pre(const unsigned short* __restrict__ Amat,
                                                    const unsigned short* __restrict__ Bmat,
                                                    unsigned short* __restrict__ q_out,
                                                    unsigned short* __restrict__ k_out,
                                                    unsigned short* __restrict__ v_out,
                                                    const float* __restrict__ adj,
                                                    const float* __restrict__ bias_scale,
                                                    unsigned short* __restrict__ EI) {
    __shared__ __align__(16) char sm[24576];
    const int tid = threadIdx.x;
    const int gb = blockIdx.x;                 // 0..1791
    const int u = gb % 7, grp = gb / 7;        // 256 groups of (3 gemm + 4 prep)

    if (u < 3) {
        // ===================== qkv GEMM body (BM=64, BN=128, K=512) =====================
        const int tile = grp * 3 + u;          // 0..767
        const int row0 = (tile / 12) * 64, col0 = (tile % 12) * 128;
        unsigned short* As = (unsigned short*)sm;            // 64*64*2  = 8 KB
        unsigned short* Bs = (unsigned short*)(sm + 8192);   // 128*64*2 = 16 KB
        const int l = tid & 63, wid = tid >> 6;
        const int g = l >> 4, c = l & 15;
        const int wr = wid >> 1, wc = wid & 1;

        f32x4 acc[2][4];
#pragma unroll
        for (int mi = 0; mi < 2; ++mi)
#pragma unroll
            for (int ni = 0; ni < 4; ++ni) acc[mi][ni] = (f32x4){0.f, 0.f, 0.f, 0.f};

        for (int k0 = 0; k0 < 512; k0 += 64) {
            bf16x8 ra[2], rb[4];
#pragma unroll
            for (int i = 0; i < 2; ++i) {
                int q = i * 256 + tid;
                int r = q >> 3, cb = (q & 7) * 16;
                ra[i] = *(const bf16x8*)((const char*)Amat + (size_t)(row0 + r) * 1024 + k0 * 2 + cb);
            }
#pragma unroll
            for (int i = 0; i < 4; ++i) {
                int q = i * 256 + tid;
                int r = q >> 3, cb = (q & 7) * 16;
                rb[i] = *(const bf16x8*)((const char*)Bmat + (size_t)(col0 + r) * 1024 + k0 * 2 + cb);
            }
            __syncthreads();
#pragma unroll
            for (int i = 0; i < 2; ++i) {
                int q = i * 256 + tid;
                int r = q >> 3, cb = (q & 7) * 16;
                *(bf16x8*)((char*)As + r * 128 + (cb ^ ((r & 7) << 4))) = ra[i];
            }
#pragma unroll
            for (int i = 0; i < 4; ++i) {
                int q = i * 256 + tid;
                int r = q >> 3, cb = (q & 7) * 16;
                *(bf16x8*)((char*)Bs + r * 128 + (cb ^ ((r & 7) << 4))) = rb[i];
            }
            __syncthreads();
#pragma unroll
            for (int kk = 0; kk < 2; ++kk) {
                bf16x8 afr[2], bfr[4];
#pragma unroll
                for (int mi = 0; mi < 2; ++mi) {
                    int r = wr * 32 + mi * 16 + c;
                    afr[mi] = *(const bf16x8*)((const char*)As + r * 128 + ((kk * 64 + g * 16) ^ ((r & 7) << 4)));
                }
#pragma unroll
                for (int ni = 0; ni < 4; ++ni) {
                    int r = wc * 64 + ni * 16 + c;
                    bfr[ni] = *(const bf16x8*)((const char*)Bs + r * 128 + ((kk * 64 + g * 16) ^ ((r & 7) << 4)));
                }
#pragma unroll
                for (int mi = 0; mi < 2; ++mi)
#pragma unroll
                    for (int ni = 0; ni < 4; ++ni)
                        acc[mi][ni] = __builtin_amdgcn_mfma_f32_16x16x32_bf16(afr[mi], bfr[ni], acc[mi][ni], 0, 0, 0);
            }
        }
#pragma unroll
        for (int mi = 0; mi < 2; ++mi) {
#pragma unroll
            for (int ni = 0; ni < 4; ++ni) {
#pragma unroll
                for (int ii = 0; ii < 4; ++ii) {
                    int m = row0 + wr * 32 + mi * 16 + g * 4 + ii;
                    int n = col0 + wc * 64 + ni * 16 + c;
                    unsigned short v = f2bf(acc[mi][ni][ii]);
                    int b = m >> 10, ll = m & 1023;
                    int which = n >> 9, cc = n & 511;
                    int hh = cc >> 6, d = cc & 63;
                    int bh = b * 8 + hh;
                    if (which == 0)      q_out[((size_t)bh * L_ + ll) * D_ + d] = v;
                    else if (which == 1) k_out[((size_t)bh * L_ + ll) * D_ + d] = v;
                    else                 v_out[((size_t)bh * D_ + d) * L_ + ll] = v;
                }
            }
        }
    } else {
        // ===================== prep_e body (round-6 non-symmetric) =====================
        const int pb = grp * 4 + (u - 3);      // 0..1023
        const int kx = pb & 15, qy = (pb >> 4) & 15, bz = pb >> 8;
        const int q0 = qy * 64, k0 = kx * 64;
        float (*Tr)[65] = (float(*)[65])sm;    // 64*65*4 = 16.6 KB
        const float* adjb = adj + (size_t)bz * L_ * L_;
#pragma unroll
        for (int i = 0; i < 4; ++i) {
            int idx = i * 256 + tid;
            int rk = idx >> 4, c4 = (idx & 15) * 4;
            float4 v = *(const float4*)(adjb + (size_t)(k0 + rk) * L_ + q0 + c4);
            Tr[rk][c4 + 0] = v.x; Tr[rk][c4 + 1] = v.y; Tr[rk][c4 + 2] = v.z; Tr[rk][c4 + 3] = v.w;
        }
        __syncthreads();
        const float bs0 = bias_scale[0], bs1 = bias_scale[1];
        const int w = tid >> 6, l = tid & 63, g = l >> 4, c = l & 15;
#pragma unroll
        for (int qs = 0; qs < 4; ++qs) {
            int ql = qs * 16 + c, qg = q0 + ql;
            int klb = w * 16 + g * 4;
            float4 af4 = *(const float4*)(adjb + (size_t)qg * L_ + k0 + klb);
            unsigned short ef[4], eb[4];
            const float afv[4] = {af4.x, af4.y, af4.z, af4.w};
#pragma unroll
            for (int e = 0; e < 4; ++e) {
                int kg = k0 + klb + e;
                bool z = (qg == 0) || (kg == 0);
                ef[e] = f2bf(z ? 1.0f : __expf(bs0 * afv[e]));
                eb[e] = f2bf(z ? 1.0f : __expf(bs1 * Tr[klb + e][ql]));
            }
            size_t o = (((size_t)bz * 64 + (qy * 4 + qs)) * 64 + (kx * 4 + w)) * 512 + (size_t)l * 8;
            *(u16x8*)(EI + o) = (u16x8){ef[0], ef[1], ef[2], ef[3], eb[0], eb[1], eb[2], eb[3]};
        }
    }
}

// ---------------- proj GEMM: out[M,512] = hb[M,512] * wproj[512,512]^T ----------------
template <int BM, int BN, int KDIM, int NDIM>
__global__ __launch_bounds__(256, 4) void gemm_proj(const unsigned short* __restrict__ Amat,
                                                    const unsigned short* __restrict__ Bmat,
                                                    float* __restrict__ outp) {
    constexpr int NA = BM / 32, NB = BN / 32;
    constexpr int MI = BM / 32, NI = BN / 32;
    __shared__ __align__(16) unsigned short As[BM * 64];
    __shared__ __align__(16) unsigned short Bs[BN * 64];
    const int tid = threadIdx.x;
    const int l = tid & 63, wid = tid >> 6;
    const int g = l >> 4, c = l & 15;
    const int wr = wid >> 1, wc = wid & 1;
    const int row0 = blockIdx.y * BM, col0 = blockIdx.x * BN;

    f32x4 acc[MI][NI];
#pragma unroll
    for (int mi = 0; mi < MI; ++mi)
#pragma unroll
        for (int ni = 0; ni < NI; ++ni) acc[mi][ni] = (f32x4){0.f, 0.f, 0.f, 0.f};

    for (int k0 = 0; k0 < KDIM; k0 += 64) {
        bf16x8 ra[NA], rb[NB];
#pragma unroll
        for (int i = 0; i < NA; ++i) {
            int q = i * 256 + tid;
            int r = q >> 3, cb = (q & 7) * 16;
            ra[i] = *(const bf16x8*)((const char*)Amat + (size_t)(row0 + r) * (KDIM * 2) + k0 * 2 + cb);
        }
#pragma unroll
        for (int i = 0; i < NB; ++i) {
            int q = i * 256 + tid;
            int r = q >> 3, cb = (q & 7) * 16;
            rb[i] = *(const bf16x8*)((const char*)Bmat + (size_t)(col0 + r) * (KDIM * 2) + k0 * 2 + cb);
        }
        __syncthreads();
#pragma unroll
        for (int i = 0; i < NA; ++i) {
            int q = i * 256 + tid;
            int r = q >> 3, cb = (q & 7) * 16;
            *(bf16x8*)((char*)As + r * 128 + (cb ^ ((r & 7) << 4))) = ra[i];
        }
#pragma unroll
        for (int i = 0; i < NB; ++i) {
            int q = i * 256 + tid;
            int r = q >> 3, cb = (q & 7) * 16;
            *(bf16x8*)((char*)Bs + r * 128 + (cb ^ ((r & 7) << 4))) = rb[i];
        }
        __syncthreads();
#pragma unroll
        for (int kk = 0; kk < 2; ++kk) {
            bf16x8 afr[MI], bfr[NI];
#pragma unroll
            for (int mi = 0; mi < MI; ++mi) {
                int r = wr * (BM / 2) + mi * 16 + c;
                afr[mi] = *(const bf16x8*)((const char*)As + r * 128 + ((kk * 64 + g * 16) ^ ((r & 7) << 4)));
            }
#pragma unroll
            for (int ni = 0; ni < NI; ++ni) {
                int r = wc * (BN / 2) + ni * 16 + c;
                bfr[ni] = *(const bf16x8*)((const char*)Bs + r * 128 + ((kk * 64 + g * 16) ^ ((r & 7) << 4)));
            }
#pragma unroll
            for (int mi = 0; mi < MI; ++mi)
#pragma unroll
                for (int ni = 0; ni < NI; ++ni)
                    acc[mi][ni] = __builtin_amdgcn_mfma_f32_16x16x32_bf16(afr[mi], bfr[ni], acc[mi][ni], 0, 0, 0);
        }
    }
#pragma unroll
    for (int mi = 0; mi < MI; ++mi)
#pragma unroll
        for (int ni = 0; ni < NI; ++ni)
#pragma unroll
            for (int ii = 0; ii < 4; ++ii) {
                int m = row0 + wr * (BM / 2) + mi * 16 + g * 4 + ii;
                int n = col0 + wc * (BN / 2) + ni * 16 + c;
                outp[(size_t)m * NDIM + n] = acc[mi][ni][ii];
            }
}

// ---------------- fused 3-branch attention: round-6 structure (best known, unchanged) ----------------
struct EReg { bf16x8 e[4]; };

__global__ __launch_bounds__(256, 2) void attn_kernel(const unsigned short* __restrict__ Qb,
                                                      const unsigned short* __restrict__ Kb,
                                                      const unsigned short* __restrict__ Vtb,
                                                      const unsigned short* __restrict__ EI,
                                                      const float* __restrict__ beta,
                                                      unsigned short* __restrict__ hb) {
    // per buffer (16KB): K tile 8KB | V tile 8KB
    __shared__ __align__(16) char smem[2][16384];
    const int tid = threadIdx.x;
    const int w = tid >> 6, l = tid & 63;
    const int g = l >> 4, c = l & 15;

    // XCD-grouping swizzle: 8 head-blocks sharing one (b,q64) EI slice -> same XCD.
    const int p = blockIdx.x;                 // 0..511
    const int s = (p & 7) + 8 * (p >> 6);     // (b, qb) index 0..63
    const int h = (p >> 3) & 7;
    const int b = s >> 4, qb = s & 15;
    const int bh = b * 8 + h;
    const int q0 = qb * 64 + w * 16;
    const int qt = qb * 4 + w;

    const unsigned short* Qrow = Qb + ((size_t)bh * L_ + q0 + c) * D_;
    const bf16x8 qf0 = *(const bf16x8*)(Qrow + g * 8);
    const bf16x8 qf1 = *(const bf16x8*)(Qrow + 32 + g * 8);

    const unsigned short* Kbase = Kb + (size_t)bh * L_ * D_;   // row stride 64
    const unsigned short* Vbase = Vtb + (size_t)bh * D_ * L_;  // row stride 1024
    const unsigned short* Ebase = EI + ((size_t)(b * 64 + qt) * 64) * 512;

    f32x4 O[3][4];
#pragma unroll
    for (int j = 0; j < 3; ++j)
#pragma unroll
        for (int dc = 0; dc < 4; ++dc) O[j][dc] = (f32x4){0.f, 0.f, 0.f, 0.f};
    float lsum0 = 0.f, lsum1 = 0.f, lsum2 = 0.f;

    const int srow = l >> 3, sm = l & 7;       // staging row-within-8, chunk
    const int key = (c & 7) << 4;              // read-side swizzle key

    auto stage = [&](int t, char* base) {
#pragma unroll
        for (int n = 0; n < 2; ++n) {
            int i = 2 * w + n;
            int row = i * 8 + srow;
            int sw = (sm ^ (row & 7)) * 8;     // pre-swizzled global source
            gload16(Kbase + (size_t)(t * 64 + row) * D_ + sw, base + i * 1024);
            gload16(Vbase + (size_t)row * L_ + t * 64 + sw, base + 8192 + i * 1024);
        }
    };
    auto eload = [&](EReg& X, int t) {
#pragma unroll
        for (int ks = 0; ks < 4; ++ks)
            X.e[ks] = *(const bf16x8*)(Ebase + (size_t)(t * 4 + ks) * 512 + l * 8);
    };

    auto compute = [&](const char* base, const EReg& E) {
        const char* Kl = base;
        const char* Vl = base + 8192;
        unsigned rr[4][3][2];
#pragma unroll
        for (int st = 0; st < 4; ++st) {
            const char* kr = Kl + (st * 16 + c) * 128;
            bf16x8 ka = *(const bf16x8*)(kr + ((g * 16) ^ key));
            bf16x8 kb = *(const bf16x8*)(kr + ((64 + g * 16) ^ key));
            f32x4 sacc = (f32x4){0.f, 0.f, 0.f, 0.f};
            sacc = __builtin_amdgcn_mfma_f32_16x16x32_bf16(ka, qf0, sacc, 0, 0, 0);
            sacc = __builtin_amdgcn_mfma_f32_16x16x32_bf16(kb, qf1, sacc, 0, 0, 0);
            float pv[3][4];
#pragma unroll
            for (int i = 0; i < 4; ++i) {
                float p0 = __expf(sacc[i] * 0.125f);
                float p1 = p0 * bf2f((unsigned short)E.e[st][i]);
                float p2 = p0 * bf2f((unsigned short)E.e[st][4 + i]);
                lsum0 += p0; lsum1 += p1; lsum2 += p2;
                pv[0][i] = p0; pv[1][i] = p1; pv[2][i] = p2;
            }
#pragma unroll
            for (int j = 0; j < 3; ++j) {
                rr[st][j][0] = __builtin_amdgcn_perm(__float_as_uint(pv[j][1]), __float_as_uint(pv[j][0]), 0x07060302u);
                rr[st][j][1] = __builtin_amdgcn_perm(__float_as_uint(pv[j][3]), __float_as_uint(pv[j][2]), 0x07060302u);
            }
        }
#pragma unroll
        for (int kk = 0; kk < 2; ++kk) {
            bf16x8 af[3];
#pragma unroll
            for (int j = 0; j < 3; ++j) {
                union { unsigned u[4]; bf16x8 v; } t_;
                t_.u[0] = rr[2 * kk][j][0];     t_.u[1] = rr[2 * kk][j][1];
                t_.u[2] = rr[2 * kk + 1][j][0]; t_.u[3] = rr[2 * kk + 1][j][1];
                af[j] = t_.v;
            }
#pragma unroll
            for (int dc = 0; dc < 4; ++dc) {
                const char* vr = Vl + (dc * 16 + c) * 128;
                u32x2 vlo = *(const u32x2*)(vr + ((kk * 64 + g * 8) ^ key));
                u32x2 vhi = *(const u32x2*)(vr + ((kk * 64 + 32 + g * 8) ^ key));
                union { unsigned u[4]; bf16x8 v; } bv;
                bv.u[0] = vlo[0]; bv.u[1] = vlo[1]; bv.u[2] = vhi[0]; bv.u[3] = vhi[1];
#pragma unroll
                for (int j = 0; j < 3; ++j)
                    O[j][dc] = __builtin_amdgcn_mfma_f32_16x16x32_bf16(af[j], bv.v, O[j][dc], 0, 0, 0);
            }
        }
    };

    EReg E0, E1;
    stage(0, smem[0]);
    eload(E0, 0);
    __syncthreads();
#pragma unroll 1
    for (int t = 0; t < 16; t += 2) {
        stage(t + 1, smem[1]);
        eload(E1, t + 1);
        compute(smem[0], E0);
        __syncthreads();
        if (t + 2 < 16) { stage(t + 2, smem[0]); eload(E0, t + 2); }
        compute(smem[1], E1);
        __syncthreads();
    }

    // reduce lsum over g-groups (k partitioned across g)
    lsum0 += __shfl_xor(lsum0, 16); lsum0 += __shfl_xor(lsum0, 32);
    lsum1 += __shfl_xor(lsum1, 16); lsum1 += __shfl_xor(lsum1, 32);
    lsum2 += __shfl_xor(lsum2, 16); lsum2 += __shfl_xor(lsum2, 32);

    float b0 = beta[0], b1 = beta[1], b2 = beta[2];
    float bm = fmaxf(b0, fmaxf(b1, b2));
    float e0 = __expf(b0 - bm), e1 = __expf(b1 - bm), e2 = __expf(b2 - bm);
    float inv = 1.0f / (e0 + e1 + e2);
    float i0 = e0 * inv / lsum0, i1 = e1 * inv / lsum1, i2 = e2 * inv / lsum2;

    float iq0[4], iq1[4], iq2[4];
#pragma unroll
    for (int ii = 0; ii < 4; ++ii) {
        iq0[ii] = __shfl(i0, g * 4 + ii);
        iq1[ii] = __shfl(i1, g * 4 + ii);
        iq2[ii] = __shfl(i2, g * 4 + ii);
    }
    const int hcol = (bh & 7) * 64;
#pragma unroll
    for (int dc = 0; dc < 4; ++dc) {
#pragma unroll
        for (int ii = 0; ii < 4; ++ii) {
            float hv = iq0[ii] * O[0][dc][ii] + iq1[ii] * O[1][dc][ii] + iq2[ii] * O[2][dc][ii];
            int qrow = q0 + g * 4 + ii;
            hb[((size_t)(b << 10) + qrow) * C_ + hcol + dc * 16 + c] = f2bf(hv);
        }
    }
}

extern "C" void kernel_launch(void* const* d_in, const int* in_sizes, int n_in,
                              void* d_out, int out_size, void* d_ws, size_t ws_size,
                              hipStream_t stream) {
    const float* x          = (const float*)d_in[0];
    const float* adj        = (const float*)d_in[1];
    const float* wqkv       = (const float*)d_in[2];
    const float* wproj      = (const float*)d_in[3];
    const float* bias_scale = (const float*)d_in[4];
    const float* beta       = (const float*)d_in[5];
    float* out = (float*)d_out;

    char* ws = (char*)d_ws;
    size_t off = 0;
    auto alloc = [&](size_t bytes) {
        void* p = ws + off;
        off += (bytes + 255) & ~(size_t)255;
        return p;
    };
    unsigned short* xb     = (unsigned short*)alloc((size_t)M_ * C_ * 2);
    unsigned short* wqkvb  = (unsigned short*)alloc((size_t)3 * C_ * C_ * 2);
    unsigned short* wprojb = (unsigned short*)alloc((size_t)C_ * C_ * 2);
    unsigned short* Qb     = (unsigned short*)alloc((size_t)BH_ * L_ * D_ * 2);
    unsigned short* Kb     = (unsigned short*)alloc((size_t)BH_ * L_ * D_ * 2);
    unsigned short* Vtb    = (unsigned short*)alloc((size_t)BH_ * D_ * L_ * 2);
    unsigned short* EI     = (unsigned short*)alloc((size_t)B_ * L_ * L_ * 4);  // ef+eb: B*L*L*2 bf16
    unsigned short* hb     = (unsigned short*)alloc((size_t)M_ * C_ * 2);

    cvt_all<<<(NX4 + NWQ4 + NWP4 + 255) / 256, 256, 0, stream>>>(x, wqkv, wproj, xb, wqkvb, wprojb);
    fused_pre<<<dim3(1792), 256, 0, stream>>>(xb, wqkvb, Qb, Kb, Vtb, adj, bias_scale, EI);
    attn_kernel<<<dim3(512), 256, 0, stream>>>(Qb, Kb, Vtb, EI, beta, hb);
    gemm_proj<64, 64, 512, 512><<<dim3(512 / 64, M_ / 64), 256, 0, stream>>>(hb, wprojb, out);
}